// Round 5
// baseline (534.457 us; speedup 1.0000x reference)
//
#include <hip/hip_runtime.h>
#include <math.h>

#define NB 2048
#define NL 256
#define NH 512

typedef unsigned short ushort_t;
typedef short s16x8 __attribute__((ext_vector_type(8)));
typedef short s16x4 __attribute__((ext_vector_type(4)));
typedef float f32x4 __attribute__((ext_vector_type(4)));

__device__ __forceinline__ float wsum(float v){
  #pragma unroll
  for (int o = 32; o; o >>= 1) v += __shfl_xor(v, o);
  return v;
}
__device__ __forceinline__ float wmax(float v){
  #pragma unroll
  for (int o = 32; o; o >>= 1) v = fmaxf(v, __shfl_xor(v, o));
  return v;
}
__device__ __forceinline__ ushort_t f2bf(float f){
  union { float f; unsigned u; } v; v.f = f;
  unsigned r = v.u + 0x7fffu + ((v.u >> 16) & 1u);
  return (ushort_t)(r >> 16);
}

// ---------------------------------------------------------------------------
// kPrepAll (1133 blocks x 256): all preprocessing in one launch.
//  bid <  512: hidden fp32 -> bf16 into A2 right half (lda 1024)
//  bid <  544: WTA[c][k] = fp32 attn_W_bottom^T   (256x512)
//  bid <  608: WTC[c][k] = fp32 comb_W_bottom^T   (512x512)
//  bid < 1120: WTG[n][k] bf16 gate-interleaved blockdiag GRU weight (2048x1024)
//  bid < 1132: p,q (attn top rank-2) / p2,q2 (comb top rank-2)
//  bid ==1132: stats = {mW, mb, Su2, Suv, Sv2}
// ---------------------------------------------------------------------------
__global__ __launch_bounds__(256)
void kPrepAll(const float* __restrict__ hidden,
              const float* __restrict__ eW, const float* __restrict__ eb,
              const float* __restrict__ attn_W, const float* __restrict__ comb_W,
              const float* __restrict__ Wih, const float* __restrict__ Whh,
              ushort_t* __restrict__ A2, float* __restrict__ WTA,
              float* __restrict__ WTC, ushort_t* __restrict__ WTG,
              float* __restrict__ stats,
              float* __restrict__ p, float* __restrict__ q,
              float* __restrict__ p2, float* __restrict__ q2)
{
  const int bid = blockIdx.x, tid = threadIdx.x;
  if (bid < 512) {                       // hidden -> bf16 A2 right half
    const int idx = (bid*256 + tid) * 8;
    const int b = idx >> 9, h = idx & 511;
    float4 v0 = *(const float4*)(hidden + idx);
    float4 v1 = *(const float4*)(hidden + idx + 4);
    s16x8 o;
    o[0]=f2bf(v0.x); o[1]=f2bf(v0.y); o[2]=f2bf(v0.z); o[3]=f2bf(v0.w);
    o[4]=f2bf(v1.x); o[5]=f2bf(v1.y); o[6]=f2bf(v1.z); o[7]=f2bf(v1.w);
    *(s16x8*)&A2[(size_t)b*1024 + 512 + h] = o;
    return;
  }
  if (bid < 544) {                       // WTA fp32 transpose
    const int b2 = bid - 512, bx = b2 & 3, by = b2 >> 2;
    const int c = bx*64 + (tid & 63);
    const int ksub = by*64 + (tid >> 6)*16;
    float vals[16];
    #pragma unroll
    for (int kk = 0; kk < 16; ++kk)
      vals[kk] = attn_W[(size_t)(512 + ksub + kk)*NL + c];
    #pragma unroll
    for (int kk = 0; kk < 4; ++kk)
      *(float4*)&WTA[(size_t)c*512 + ksub + kk*4] = *(float4*)&vals[kk*4];
    return;
  }
  if (bid < 608) {                       // WTC fp32 transpose
    const int b2 = bid - 544, bx = b2 & 7, by = b2 >> 3;
    const int c = bx*64 + (tid & 63);
    const int ksub = by*64 + (tid >> 6)*16;
    float vals[16];
    #pragma unroll
    for (int kk = 0; kk < 16; ++kk)
      vals[kk] = comb_W[(size_t)(512 + ksub + kk)*NH + c];
    #pragma unroll
    for (int kk = 0; kk < 4; ++kk)
      *(float4*)&WTC[(size_t)c*512 + ksub + kk*4] = *(float4*)&vals[kk*4];
    return;
  }
  if (bid < 1120) {                      // WTG bf16 gate-blockdiag
    const int b2 = bid - 608, bx = b2 & 31, by = b2 >> 5;
    const int n = bx*64 + (tid & 63);
    const int ksub = by*64 + (tid >> 6)*16;
    const int g = n >> 6, t = (n >> 4) & 3, c = (g << 4) | (n & 15);
    const int sc = (t == 0) ? c : (t == 1) ? (512 + c) : (1024 + c);
    ushort_t vals[16];
    #pragma unroll
    for (int kk = 0; kk < 16; ++kk) {
      int k = ksub + kk;
      float v;
      if (k < 512) v = (t == 3) ? 0.f : Wih[(size_t)k*1536 + sc];
      else         v = (t == 2) ? 0.f : Whh[(size_t)(k-512)*1536 + sc];
      vals[kk] = f2bf(v);
    }
    *(s16x8*)&WTG[(size_t)n*1024 + ksub]     = *(s16x8*)&vals[0];
    *(s16x8*)&WTG[(size_t)n*1024 + ksub + 8] = *(s16x8*)&vals[8];
    return;
  }
  // rank-2 projections + stats: each block computes mW,mb locally first
  {
    __shared__ float rw[4], rb[4];
    __shared__ float pa[4][64], pb[4][64];
    const int lane = tid & 63, wv = tid >> 6;
    float swv = eW[tid] + eW[tid + 256];
    float sbv = eb[tid] + eb[tid + 256];
    swv = wsum(swv); sbv = wsum(sbv);
    if (lane == 0) { rw[wv] = swv; rb[wv] = sbv; }
    __syncthreads();
    const float mW = (rw[0]+rw[1]+rw[2]+rw[3]) * (1.f/NH);
    const float mb = (rb[0]+rb[1]+rb[2]+rb[3]) * (1.f/NH);

    if (bid == 1132) {
      float u0 = eW[tid]-mW, u1 = eW[tid+256]-mW;
      float v0 = eb[tid]-mb, v1 = eb[tid+256]-mb;
      float s2 = u0*u0 + u1*u1, s3 = u0*v0 + u1*v1, s4 = v0*v0 + v1*v1;
      s2 = wsum(s2); s3 = wsum(s3); s4 = wsum(s4);
      if (lane == 0) { pa[0][wv] = s2; pa[1][wv] = s3; pa[2][wv] = s4; }
      __syncthreads();
      if (tid == 0) {
        stats[0] = mW; stats[1] = mb;
        stats[2] = pa[0][0]+pa[0][1]+pa[0][2]+pa[0][3];
        stats[3] = pa[1][0]+pa[1][1]+pa[1][2]+pa[1][3];
        stats[4] = pa[2][0]+pa[2][1]+pa[2][2]+pa[2][3];
      }
      return;
    }
    const int bid2 = bid - 1120;
    const float* Wsrc; int ldw, c0; float *op, *oq;
    if (bid2 < 4) { Wsrc = attn_W; ldw = NL; c0 = bid2*64;     op = p  + c0; oq = q  + c0; }
    else          { Wsrc = comb_W; ldw = NH; c0 = (bid2-4)*64; op = p2 + c0; oq = q2 + c0; }
    const int c = c0 + lane;
    const int hc = tid >> 6;
    float ap = 0.f, aq = 0.f;
    #pragma unroll 4
    for (int h = hc*128; h < hc*128 + 128; ++h) {
      float w = Wsrc[(size_t)h*ldw + c];
      ap = fmaf(eW[h]-mW, w, ap);
      aq = fmaf(eb[h]-mb, w, aq);
    }
    pa[hc][lane] = ap; pb[hc][lane] = aq;
    __syncthreads();
    if (hc == 0) {
      op[lane] = pa[0][lane]+pa[1][lane]+pa[2][lane]+pa[3][lane];
      oq[lane] = pb[0][lane]+pb[1][lane]+pb[2][lane]+pb[3][lane];
    }
  }
}

// ---------------------------------------------------------------------------
// k2fused (2048 blocks x 128), per batch b:
//  A: logits[256] = h0 . WTA^T + attn_b + rank2(e)   (fp32, L2)
//     softmax -> attn_out (d_out) + wl (LDS)
//  B: a[512] = sum_l wl[l]*enc[b,l,:]                (1.07 GB HBM stream)
//  C: xt[512] = relu(a . WTC^T + comb_b + rank2(e))  (fp32, L2) -> bf16 A2
//     NOTE: xt is 512 elems -> write s16x4 per thread (tid*4), NOT s16x8;
//     an s16x8 write at tid*8 would clobber the h0 half of A2 (round-4 bug).
// ---------------------------------------------------------------------------
__global__ __launch_bounds__(128)
void k2fused(const float* __restrict__ x, const float* __restrict__ hidden,
             const float* __restrict__ enc,
             const float* __restrict__ WTA, const float* __restrict__ attn_b,
             const float* __restrict__ p, const float* __restrict__ q,
             const float* __restrict__ WTC, const float* __restrict__ comb_b,
             const float* __restrict__ p2, const float* __restrict__ q2,
             const float* __restrict__ stats,
             float* __restrict__ attn_out, ushort_t* __restrict__ A2)
{
  __shared__ __align__(16) float h0s[NH];
  __shared__ __align__(16) float a_s[NH];
  __shared__ float wl[NL];
  __shared__ float sred[2];
  __shared__ __align__(16) ushort_t xt_s[NH];
  const int tid = threadIdx.x, lane = tid & 63, wv = tid >> 6;
  const int b = blockIdx.x;

  ((float4*)h0s)[tid] = ((const float4*)(hidden + (size_t)b*NH))[tid];
  __syncthreads();

  const float xv = x[b];
  const float rs = rsqrtf((xv*xv*stats[2] + 2.f*xv*stats[3] + stats[4])*(1.0f/NH) + 1e-5f);
  const float al = xv*rs, be = rs;

  // --- phase A: logits + softmax
  float lg[2];
  #pragma unroll
  for (int cc = 0; cc < 2; ++cc) {
    const int c = tid + cc*128;
    const float4* wrow = (const float4*)(WTA + (size_t)c*512);
    float acc = 0.f;
    #pragma unroll 8
    for (int kq = 0; kq < 128; ++kq) {
      float4 w = wrow[kq];
      const float* h4 = &h0s[kq*4];
      acc = fmaf(w.x,h4[0],fmaf(w.y,h4[1],fmaf(w.z,h4[2],fmaf(w.w,h4[3],acc))));
    }
    lg[cc] = acc + attn_b[c] + al*p[c] + be*q[c];
  }
  float m = wmax(fmaxf(lg[0], lg[1]));
  if (lane == 0) sred[wv] = m;
  __syncthreads();
  m = fmaxf(sred[0], sred[1]);
  __syncthreads();
  float e0 = expf(lg[0]-m), e1 = expf(lg[1]-m);
  float s = wsum(e0 + e1);
  if (lane == 0) sred[wv] = s;
  __syncthreads();
  const float inv = 1.f / (sred[0] + sred[1]);
  e0 *= inv; e1 *= inv;
  wl[tid] = e0; wl[tid+128] = e1;
  attn_out[(size_t)b*NL + tid]       = e0;
  attn_out[(size_t)b*NL + tid + 128] = e1;
  __syncthreads();

  // --- phase B: stream enc
  const float4* ep = (const float4*)(enc + (size_t)b*NL*NH);
  float4 acc = {0.f,0.f,0.f,0.f};
  #pragma unroll 4
  for (int l = 0; l < NL; ++l) {
    float wv2 = wl[l];
    float4 e = ep[l*(NH/4) + tid];
    acc.x = fmaf(wv2,e.x,acc.x); acc.y = fmaf(wv2,e.y,acc.y);
    acc.z = fmaf(wv2,e.z,acc.z); acc.w = fmaf(wv2,e.w,acc.w);
  }
  ((float4*)a_s)[tid] = acc;
  __syncthreads();

  // --- phase C: xt = relu(a @ WTC^T + comb_b + rank2) -> bf16
  #pragma unroll
  for (int cc = 0; cc < 4; ++cc) {
    const int c = tid + cc*128;
    const float4* wrow = (const float4*)(WTC + (size_t)c*512);
    const float4* a4 = (const float4*)a_s;
    float acc2 = comb_b[c] + al*p2[c] + be*q2[c];
    #pragma unroll 8
    for (int kq = 0; kq < 128; ++kq) {
      float4 w = wrow[kq];
      float4 av = a4[kq];
      acc2 = fmaf(w.x,av.x,fmaf(w.y,av.y,fmaf(w.z,av.z,fmaf(w.w,av.w,acc2))));
    }
    xt_s[c] = f2bf(fmaxf(acc2, 0.f));
  }
  __syncthreads();
  *(s16x4*)&A2[(size_t)b*1024 + tid*4] = *(s16x4*)&xt_s[tid*4];
}

// ---------------------------------------------------------------------------
// gemmGRU: 128x64 tile, 4 waves (4x1), wave = 32x64 (2x4 frags of 16x16x32).
// A = [xt|h0] bf16 (lda 1024), Bt = WTG (2048x1024). Epilogue: GRU gates
// (j = gate index: 0=r 1=z 2=i_n 3=h_n) -> h_new fp32.
// ---------------------------------------------------------------------------
__global__ __launch_bounds__(256)
void gemmGRU(const ushort_t* __restrict__ A, const ushort_t* __restrict__ Bt,
             const float* __restrict__ bih, const float* __restrict__ bhh,
             const float* __restrict__ hidden, float* __restrict__ h_out)
{
  __shared__ ushort_t As[128][72];
  __shared__ ushort_t Bs[64][72];
  const int tid = threadIdx.x, lane = tid & 63, wr = tid >> 6;
  const int m0 = blockIdx.x * 128, n0 = blockIdx.y * 64;
  const int K = 1024;

  f32x4 acc[2][4];
  #pragma unroll
  for (int i = 0; i < 2; ++i)
    #pragma unroll
    for (int j = 0; j < 4; ++j)
      acc[i][j] = (f32x4){0.f,0.f,0.f,0.f};

  const int srow = tid >> 3, scol = (tid & 7) * 8;
  for (int kt = 0; kt < K; kt += 64) {
    __syncthreads();
    #pragma unroll
    for (int it = 0; it < 4; ++it) {
      const int r = srow + it*32;
      *(s16x8*)&As[r][scol] = *(const s16x8*)&A[(size_t)(m0+r)*1024 + kt + scol];
    }
    #pragma unroll
    for (int it = 0; it < 2; ++it) {
      const int r = srow + it*32;
      *(s16x8*)&Bs[r][scol] = *(const s16x8*)&Bt[(size_t)(n0+r)*K + kt + scol];
    }
    __syncthreads();
    #pragma unroll
    for (int ks = 0; ks < 2; ++ks) {
      const int ko = ks*32 + (lane >> 4)*8;
      s16x8 af[2], bfr[4];
      #pragma unroll
      for (int i = 0; i < 2; ++i) af[i]  = *(const s16x8*)&As[wr*32 + i*16 + (lane & 15)][ko];
      #pragma unroll
      for (int j = 0; j < 4; ++j) bfr[j] = *(const s16x8*)&Bs[j*16 + (lane & 15)][ko];
      #pragma unroll
      for (int i = 0; i < 2; ++i)
        #pragma unroll
        for (int j = 0; j < 4; ++j)
          acc[i][j] = __builtin_amdgcn_mfma_f32_16x16x32_bf16(af[i], bfr[j], acc[i][j], 0, 0, 0);
    }
  }

  const int g = n0 >> 6;
  const int hcol = (g << 4) | (lane & 15);
  const float b_r = bih[hcol]        + bhh[hcol];
  const float b_z = bih[512 + hcol]  + bhh[512 + hcol];
  const float b_i = bih[1024 + hcol];
  const float b_h = bhh[1024 + hcol];
  #pragma unroll
  for (int i = 0; i < 2; ++i) {
    #pragma unroll
    for (int reg = 0; reg < 4; ++reg) {
      const int row = m0 + wr*32 + i*16 + ((lane >> 4) << 2) + reg;
      float rv = 1.f / (1.f + expf(-(acc[i][0][reg] + b_r)));
      float zv = 1.f / (1.f + expf(-(acc[i][1][reg] + b_z)));
      float nv = tanhf(acc[i][2][reg] + b_i + rv * (acc[i][3][reg] + b_h));
      float h0v = hidden[(size_t)row*NH + hcol];
      h_out[(size_t)row*NH + hcol] = nv + zv * (h0v - nv);
    }
  }
}

// ---------------------------------------------------------------------------
// kOut (512 blocks x 256): out0[b] = dot(h_new[b], out_W) + out_b
// ---------------------------------------------------------------------------
__global__ __launch_bounds__(256)
void kOut(const float* __restrict__ h, const float* __restrict__ out_W,
          const float* __restrict__ out_b, float* __restrict__ out0)
{
  const int row = blockIdx.x * 4 + (threadIdx.x >> 6);
  const int lane = threadIdx.x & 63;
  const float4* hp = (const float4*)(h + (size_t)row*NH);
  const float4* wp = (const float4*)out_W;
  float4 h1 = hp[lane*2], h2 = hp[lane*2+1];
  float4 w1 = wp[lane*2], w2 = wp[lane*2+1];
  float d = h1.x*w1.x + h1.y*w1.y + h1.z*w1.z + h1.w*w1.w
          + h2.x*w2.x + h2.y*w2.y + h2.z*w2.z + h2.w*w2.w;
  d = wsum(d);
  if (lane == 0) out0[row] = d + out_b[0];
}

// ---------------------------------------------------------------------------
extern "C" void kernel_launch(void* const* d_in, const int* in_sizes, int n_in,
                              void* d_out, int out_size, void* d_ws, size_t ws_size,
                              hipStream_t stream)
{
  const float* x      = (const float*)d_in[0];
  const float* hidden = (const float*)d_in[1];
  const float* enc    = (const float*)d_in[2];
  const float* emb_W  = (const float*)d_in[3];
  const float* emb_b  = (const float*)d_in[4];
  const float* attn_W = (const float*)d_in[5];
  const float* attn_b = (const float*)d_in[6];
  const float* comb_W = (const float*)d_in[7];
  const float* comb_b = (const float*)d_in[8];
  const float* Wih    = (const float*)d_in[9];
  const float* Whh    = (const float*)d_in[10];
  const float* bih    = (const float*)d_in[11];
  const float* bhh    = (const float*)d_in[12];
  const float* out_W  = (const float*)d_in[13];
  const float* out_b  = (const float*)d_in[14];

  float* out      = (float*)d_out;
  float* out0     = out;                          // 2048
  float* out_h    = out + NB;                     // B*H
  float* out_attn = out + NB + (size_t)NB*NH;     // B*L

  float* wsf   = (float*)d_ws;
  float* stats = wsf;              // 16
  float* p     = wsf + 16;         // 256
  float* q     = wsf + 272;        // 256
  float* p2    = wsf + 528;        // 512
  float* q2    = wsf + 1040;       // 512
  float* WTA   = wsf + 2048;       // [256][512] fp32
  float* WTC   = wsf + 133120;     // [512][512] fp32
  ushort_t* usb = (ushort_t*)(wsf + 395264);
  ushort_t* A2  = usb;             // [2048][1024] bf16: [xt | h0]
  ushort_t* WTG = usb + 2097152;   // [2048][1024] bf16

  kPrepAll<<<1133, 256, 0, stream>>>(hidden, emb_W, emb_b, attn_W, comb_W,
                                     Wih, Whh, A2, WTA, WTC, WTG,
                                     stats, p, q, p2, q2);
  k2fused<<<NB, 128, 0, stream>>>(x, hidden, enc, WTA, attn_b, p, q,
                                  WTC, comb_b, p2, q2, stats, out_attn, A2);
  gemmGRU<<<dim3(16, 32), 256, 0, stream>>>(A2, WTG, bih, bhh, hidden, out_h);
  kOut<<<512, 256, 0, stream>>>(out_h, out_W, out_b, out0);
}

// Round 6
// 347.558 us; speedup vs baseline: 1.5377x; 1.5377x over previous
//
#include <hip/hip_runtime.h>
#include <math.h>

#define NB 2048
#define NL 256
#define NH 512

typedef unsigned short ushort_t;
typedef short s16x8 __attribute__((ext_vector_type(8)));
typedef short s16x4 __attribute__((ext_vector_type(4)));
typedef float f32x4 __attribute__((ext_vector_type(4)));

__device__ __forceinline__ float wsum(float v){
  #pragma unroll
  for (int o = 32; o; o >>= 1) v += __shfl_xor(v, o);
  return v;
}
__device__ __forceinline__ float wmax(float v){
  #pragma unroll
  for (int o = 32; o; o >>= 1) v = fmaxf(v, __shfl_xor(v, o));
  return v;
}
__device__ __forceinline__ ushort_t f2bf(float f){
  union { float f; unsigned u; } v; v.f = f;
  unsigned r = v.u + 0x7fffu + ((v.u >> 16) & 1u);
  return (ushort_t)(r >> 16);
}

// ---------------------------------------------------------------------------
// kPrepAll (1045 blocks x 256):
//  bid <  512: hidden fp32 -> bf16 into A2 right half (lda 1024)
//  bid < 1024: WTG[n][k] bf16 gate-interleaved blockdiag GRU weight (2048x1024)
//  bid < 1036: p,q (attn top rank-2) / p2,q2 (comb top rank-2)
//  bid ==1036: stats = {mW, mb, Su2, Suv, Sv2}
//  bid < 1045: out0[b] = out_b[0]  (accumulator init for gemmGRU atomics)
// ---------------------------------------------------------------------------
__global__ __launch_bounds__(256)
void kPrepAll(const float* __restrict__ hidden,
              const float* __restrict__ eW, const float* __restrict__ eb,
              const float* __restrict__ attn_W, const float* __restrict__ comb_W,
              const float* __restrict__ Wih, const float* __restrict__ Whh,
              const float* __restrict__ out_b,
              ushort_t* __restrict__ A2, ushort_t* __restrict__ WTG,
              float* __restrict__ stats,
              float* __restrict__ p, float* __restrict__ q,
              float* __restrict__ p2, float* __restrict__ q2,
              float* __restrict__ out0)
{
  const int bid = blockIdx.x, tid = threadIdx.x;
  if (bid < 512) {                       // hidden -> bf16 A2 right half
    const int idx = (bid*256 + tid) * 8;
    const int b = idx >> 9, h = idx & 511;
    float4 v0 = *(const float4*)(hidden + idx);
    float4 v1 = *(const float4*)(hidden + idx + 4);
    s16x8 o;
    o[0]=f2bf(v0.x); o[1]=f2bf(v0.y); o[2]=f2bf(v0.z); o[3]=f2bf(v0.w);
    o[4]=f2bf(v1.x); o[5]=f2bf(v1.y); o[6]=f2bf(v1.z); o[7]=f2bf(v1.w);
    *(s16x8*)&A2[(size_t)b*1024 + 512 + h] = o;
    return;
  }
  if (bid < 1024) {                      // WTG bf16 gate-blockdiag
    const int b2 = bid - 512, bx = b2 & 31, by = b2 >> 5;
    const int n = bx*64 + (tid & 63);
    const int ksub = by*64 + (tid >> 6)*16;
    const int g = n >> 6, t = (n >> 4) & 3, c = (g << 4) | (n & 15);
    const int sc = (t == 0) ? c : (t == 1) ? (512 + c) : (1024 + c);
    ushort_t vals[16];
    #pragma unroll
    for (int kk = 0; kk < 16; ++kk) {
      int k = ksub + kk;
      float v;
      if (k < 512) v = (t == 3) ? 0.f : Wih[(size_t)k*1536 + sc];
      else         v = (t == 2) ? 0.f : Whh[(size_t)(k-512)*1536 + sc];
      vals[kk] = f2bf(v);
    }
    *(s16x8*)&WTG[(size_t)n*1024 + ksub]     = *(s16x8*)&vals[0];
    *(s16x8*)&WTG[(size_t)n*1024 + ksub + 8] = *(s16x8*)&vals[8];
    return;
  }
  if (bid >= 1037) {                     // out0 init
    out0[(bid-1037)*256 + tid] = out_b[0];
    return;
  }
  // rank-2 projections + stats
  {
    __shared__ float rw[4], rb[4];
    __shared__ float pa[4][64], pb[4][64];
    const int lane = tid & 63, wv = tid >> 6;
    float swv = eW[tid] + eW[tid + 256];
    float sbv = eb[tid] + eb[tid + 256];
    swv = wsum(swv); sbv = wsum(sbv);
    if (lane == 0) { rw[wv] = swv; rb[wv] = sbv; }
    __syncthreads();
    const float mW = (rw[0]+rw[1]+rw[2]+rw[3]) * (1.f/NH);
    const float mb = (rb[0]+rb[1]+rb[2]+rb[3]) * (1.f/NH);

    if (bid == 1036) {
      float u0 = eW[tid]-mW, u1 = eW[tid+256]-mW;
      float v0 = eb[tid]-mb, v1 = eb[tid+256]-mb;
      float s2 = u0*u0 + u1*u1, s3 = u0*v0 + u1*v1, s4 = v0*v0 + v1*v1;
      s2 = wsum(s2); s3 = wsum(s3); s4 = wsum(s4);
      if (lane == 0) { pa[0][wv] = s2; pa[1][wv] = s3; pa[2][wv] = s4; }
      __syncthreads();
      if (tid == 0) {
        stats[0] = mW; stats[1] = mb;
        stats[2] = pa[0][0]+pa[0][1]+pa[0][2]+pa[0][3];
        stats[3] = pa[1][0]+pa[1][1]+pa[1][2]+pa[1][3];
        stats[4] = pa[2][0]+pa[2][1]+pa[2][2]+pa[2][3];
      }
      return;
    }
    const int bid2 = bid - 1024;
    const float* Wsrc; int ldw, c0; float *op, *oq;
    if (bid2 < 4) { Wsrc = attn_W; ldw = NL; c0 = bid2*64;     op = p  + c0; oq = q  + c0; }
    else          { Wsrc = comb_W; ldw = NH; c0 = (bid2-4)*64; op = p2 + c0; oq = q2 + c0; }
    const int c = c0 + lane;
    const int hc = tid >> 6;
    float ap = 0.f, aq = 0.f;
    #pragma unroll 4
    for (int h = hc*128; h < hc*128 + 128; ++h) {
      float w = Wsrc[(size_t)h*ldw + c];
      ap = fmaf(eW[h]-mW, w, ap);
      aq = fmaf(eb[h]-mb, w, aq);
    }
    pa[hc][lane] = ap; pb[hc][lane] = aq;
    __syncthreads();
    if (hc == 0) {
      op[lane] = pa[0][lane]+pa[1][lane]+pa[2][lane]+pa[3][lane];
      oq[lane] = pb[0][lane]+pb[1][lane]+pb[2][lane]+pb[3][lane];
    }
  }
}

// ---------------------------------------------------------------------------
// k2fused (2048 blocks x 128), per batch b:
//  A: logits[256] = h0 . attn_W_bot + attn_b + rank2(e)   -- COALESCED:
//     fix k, thread c reads attn_W[(512+k)*NL + c]; h0[k] broadcast from LDS.
//  softmax -> attn_out (d_out) + wl (LDS)
//  B: a[512] = sum_l wl[l]*enc[b,l,:]   (1.07 GB HBM stream)
//  C: xt[512] = relu(a . comb_W_bot + comb_b + rank2(e)) -> bf16 A2 left.
//     Same coalesced direct-W pattern. xt write: s16x4 at tid*4 (512 elems!).
// ---------------------------------------------------------------------------
__global__ __launch_bounds__(128)
void k2fused(const float* __restrict__ x, const float* __restrict__ hidden,
             const float* __restrict__ enc,
             const float* __restrict__ attn_W, const float* __restrict__ attn_b,
             const float* __restrict__ p, const float* __restrict__ q,
             const float* __restrict__ comb_W, const float* __restrict__ comb_b,
             const float* __restrict__ p2, const float* __restrict__ q2,
             const float* __restrict__ stats,
             float* __restrict__ attn_out, ushort_t* __restrict__ A2)
{
  __shared__ __align__(16) float h0s[NH];
  __shared__ __align__(16) float a_s[NH];
  __shared__ float wl[NL];
  __shared__ float sred[2];
  __shared__ __align__(16) ushort_t xt_s[NH];
  const int tid = threadIdx.x, lane = tid & 63, wv = tid >> 6;
  const int b = blockIdx.x;

  ((float4*)h0s)[tid] = ((const float4*)(hidden + (size_t)b*NH))[tid];
  __syncthreads();

  const float xv = x[b];
  const float rs = rsqrtf((xv*xv*stats[2] + 2.f*xv*stats[3] + stats[4])*(1.0f/NH) + 1e-5f);
  const float al = xv*rs, be = rs;

  // --- phase A: logits (coalesced direct attn_W reads) + softmax
  float lg0 = attn_b[tid]       + al*p[tid]       + be*q[tid];
  float lg1 = attn_b[tid + 128] + al*p[tid + 128] + be*q[tid + 128];
  {
    const float* wp = attn_W + (size_t)512*NL + tid;
    #pragma unroll 4
    for (int k = 0; k < NH; k += 4) {
      float4 hv = *(const float4*)&h0s[k];
      lg0 = fmaf(hv.x, wp[0*NL],     lg0); lg1 = fmaf(hv.x, wp[0*NL+128], lg1);
      lg0 = fmaf(hv.y, wp[1*NL],     lg0); lg1 = fmaf(hv.y, wp[1*NL+128], lg1);
      lg0 = fmaf(hv.z, wp[2*NL],     lg0); lg1 = fmaf(hv.z, wp[2*NL+128], lg1);
      lg0 = fmaf(hv.w, wp[3*NL],     lg0); lg1 = fmaf(hv.w, wp[3*NL+128], lg1);
      wp += 4*NL;
    }
  }
  float m = wmax(fmaxf(lg0, lg1));
  if (lane == 0) sred[wv] = m;
  __syncthreads();
  m = fmaxf(sred[0], sred[1]);
  __syncthreads();
  float e0 = expf(lg0-m), e1 = expf(lg1-m);
  float s = wsum(e0 + e1);
  if (lane == 0) sred[wv] = s;
  __syncthreads();
  const float inv = 1.f / (sred[0] + sred[1]);
  e0 *= inv; e1 *= inv;
  wl[tid] = e0; wl[tid+128] = e1;
  attn_out[(size_t)b*NL + tid]       = e0;
  attn_out[(size_t)b*NL + tid + 128] = e1;
  __syncthreads();

  // --- phase B: stream enc (the HBM-bound phase)
  {
    const float4* ep = (const float4*)(enc + (size_t)b*NL*NH);
    float4 acc = {0.f,0.f,0.f,0.f};
    #pragma unroll 4
    for (int l = 0; l < NL; ++l) {
      float wv2 = wl[l];
      float4 e = ep[l*(NH/4) + tid];
      acc.x = fmaf(wv2,e.x,acc.x); acc.y = fmaf(wv2,e.y,acc.y);
      acc.z = fmaf(wv2,e.z,acc.z); acc.w = fmaf(wv2,e.w,acc.w);
    }
    ((float4*)a_s)[tid] = acc;
  }
  __syncthreads();

  // --- phase C: xt = relu(a . comb_W_bot + comb_b + rank2) -> bf16
  {
    float c0 = comb_b[tid]     + al*p2[tid]     + be*q2[tid];
    float c1 = comb_b[tid+128] + al*p2[tid+128] + be*q2[tid+128];
    float c2 = comb_b[tid+256] + al*p2[tid+256] + be*q2[tid+256];
    float c3 = comb_b[tid+384] + al*p2[tid+384] + be*q2[tid+384];
    const float* wp = comb_W + (size_t)512*NH + tid;
    #pragma unroll 2
    for (int k = 0; k < NH; k += 4) {
      float4 av = *(const float4*)&a_s[k];
      c0 = fmaf(av.x, wp[0*NH],     c0); c1 = fmaf(av.x, wp[0*NH+128], c1);
      c2 = fmaf(av.x, wp[0*NH+256], c2); c3 = fmaf(av.x, wp[0*NH+384], c3);
      c0 = fmaf(av.y, wp[1*NH],     c0); c1 = fmaf(av.y, wp[1*NH+128], c1);
      c2 = fmaf(av.y, wp[1*NH+256], c2); c3 = fmaf(av.y, wp[1*NH+384], c3);
      c0 = fmaf(av.z, wp[2*NH],     c0); c1 = fmaf(av.z, wp[2*NH+128], c1);
      c2 = fmaf(av.z, wp[2*NH+256], c2); c3 = fmaf(av.z, wp[2*NH+384], c3);
      c0 = fmaf(av.w, wp[3*NH],     c0); c1 = fmaf(av.w, wp[3*NH+128], c1);
      c2 = fmaf(av.w, wp[3*NH+256], c2); c3 = fmaf(av.w, wp[3*NH+384], c3);
      wp += 4*NH;
    }
    xt_s[tid]     = f2bf(fmaxf(c0, 0.f));
    xt_s[tid+128] = f2bf(fmaxf(c1, 0.f));
    xt_s[tid+256] = f2bf(fmaxf(c2, 0.f));
    xt_s[tid+384] = f2bf(fmaxf(c3, 0.f));
  }
  __syncthreads();
  *(s16x4*)&A2[(size_t)b*1024 + tid*4] = *(s16x4*)&xt_s[tid*4];
}

// ---------------------------------------------------------------------------
// gemmGRU: 128x64 tile, 4 waves (4x1). A = [xt|h0] bf16 (lda 1024),
// Bt = WTG (2048x1024). Epilogue: GRU gates -> h_new fp32, plus fused
// output projection: 16-lane reduce of h_new*out_W -> atomicAdd(out0[row]).
// out0 pre-initialized to out_b by kPrepAll each launch.
// ---------------------------------------------------------------------------
__global__ __launch_bounds__(256)
void gemmGRU(const ushort_t* __restrict__ A, const ushort_t* __restrict__ Bt,
             const float* __restrict__ bih, const float* __restrict__ bhh,
             const float* __restrict__ hidden, const float* __restrict__ out_W,
             float* __restrict__ h_out, float* __restrict__ out0)
{
  __shared__ ushort_t As[128][72];
  __shared__ ushort_t Bs[64][72];
  const int tid = threadIdx.x, lane = tid & 63, wr = tid >> 6;
  const int m0 = blockIdx.x * 128, n0 = blockIdx.y * 64;
  const int K = 1024;

  f32x4 acc[2][4];
  #pragma unroll
  for (int i = 0; i < 2; ++i)
    #pragma unroll
    for (int j = 0; j < 4; ++j)
      acc[i][j] = (f32x4){0.f,0.f,0.f,0.f};

  const int srow = tid >> 3, scol = (tid & 7) * 8;
  for (int kt = 0; kt < K; kt += 64) {
    __syncthreads();
    #pragma unroll
    for (int it = 0; it < 4; ++it) {
      const int r = srow + it*32;
      *(s16x8*)&As[r][scol] = *(const s16x8*)&A[(size_t)(m0+r)*1024 + kt + scol];
    }
    #pragma unroll
    for (int it = 0; it < 2; ++it) {
      const int r = srow + it*32;
      *(s16x8*)&Bs[r][scol] = *(const s16x8*)&Bt[(size_t)(n0+r)*K + kt + scol];
    }
    __syncthreads();
    #pragma unroll
    for (int ks = 0; ks < 2; ++ks) {
      const int ko = ks*32 + (lane >> 4)*8;
      s16x8 af[2], bfr[4];
      #pragma unroll
      for (int i = 0; i < 2; ++i) af[i]  = *(const s16x8*)&As[wr*32 + i*16 + (lane & 15)][ko];
      #pragma unroll
      for (int j = 0; j < 4; ++j) bfr[j] = *(const s16x8*)&Bs[j*16 + (lane & 15)][ko];
      #pragma unroll
      for (int i = 0; i < 2; ++i)
        #pragma unroll
        for (int j = 0; j < 4; ++j)
          acc[i][j] = __builtin_amdgcn_mfma_f32_16x16x32_bf16(af[i], bfr[j], acc[i][j], 0, 0, 0);
    }
  }

  const int g = n0 >> 6;
  const int hcol = (g << 4) | (lane & 15);
  const float b_r = bih[hcol]        + bhh[hcol];
  const float b_z = bih[512 + hcol]  + bhh[512 + hcol];
  const float b_i = bih[1024 + hcol];
  const float b_h = bhh[1024 + hcol];
  const float ow  = out_W[hcol];
  #pragma unroll
  for (int i = 0; i < 2; ++i) {
    #pragma unroll
    for (int reg = 0; reg < 4; ++reg) {
      const int row = m0 + wr*32 + i*16 + ((lane >> 4) << 2) + reg;
      float rv = 1.f / (1.f + expf(-(acc[i][0][reg] + b_r)));
      float zv = 1.f / (1.f + expf(-(acc[i][1][reg] + b_z)));
      float nv = tanhf(acc[i][2][reg] + b_i + rv * (acc[i][3][reg] + b_h));
      float h0v = hidden[(size_t)row*NH + hcol];
      float hn = nv + zv * (h0v - nv);
      h_out[(size_t)row*NH + hcol] = hn;
      float partial = hn * ow;       // 16-lane (this row's 16 cols) reduce
      #pragma unroll
      for (int o = 1; o < 16; o <<= 1) partial += __shfl_xor(partial, o);
      if ((lane & 15) == 0) atomicAdd(&out0[row], partial);
    }
  }
}

// ---------------------------------------------------------------------------
extern "C" void kernel_launch(void* const* d_in, const int* in_sizes, int n_in,
                              void* d_out, int out_size, void* d_ws, size_t ws_size,
                              hipStream_t stream)
{
  const float* x      = (const float*)d_in[0];
  const float* hidden = (const float*)d_in[1];
  const float* enc    = (const float*)d_in[2];
  const float* emb_W  = (const float*)d_in[3];
  const float* emb_b  = (const float*)d_in[4];
  const float* attn_W = (const float*)d_in[5];
  const float* attn_b = (const float*)d_in[6];
  const float* comb_W = (const float*)d_in[7];
  const float* comb_b = (const float*)d_in[8];
  const float* Wih    = (const float*)d_in[9];
  const float* Whh    = (const float*)d_in[10];
  const float* bih    = (const float*)d_in[11];
  const float* bhh    = (const float*)d_in[12];
  const float* out_W  = (const float*)d_in[13];
  const float* out_b  = (const float*)d_in[14];

  float* out      = (float*)d_out;
  float* out0     = out;                          // 2048
  float* out_h    = out + NB;                     // B*H
  float* out_attn = out + NB + (size_t)NB*NH;     // B*L

  float* wsf   = (float*)d_ws;
  float* stats = wsf;              // 16
  float* p     = wsf + 16;         // 256
  float* q     = wsf + 272;        // 256
  float* p2    = wsf + 528;        // 512
  float* q2    = wsf + 1040;       // 512
  ushort_t* usb = (ushort_t*)(wsf + 2048);
  ushort_t* A2  = usb;             // [2048][1024] bf16: [xt | h0]
  ushort_t* WTG = usb + 2097152;   // [2048][1024] bf16

  kPrepAll<<<1045, 256, 0, stream>>>(hidden, emb_W, emb_b, attn_W, comb_W,
                                     Wih, Whh, out_b, A2, WTG,
                                     stats, p, q, p2, q2, out0);
  k2fused<<<NB, 128, 0, stream>>>(x, hidden, enc, attn_W, attn_b, p, q,
                                  comb_W, comb_b, p2, q2, stats, out_attn, A2);
  gemmGRU<<<dim3(16, 32), 256, 0, stream>>>(A2, WTG, bih, bhh, hidden, out_W,
                                            out_h, out0);
}

// Round 7
// 265.655 us; speedup vs baseline: 2.0119x; 1.3083x over previous
//
#include <hip/hip_runtime.h>
#include <math.h>

#define NB 2048
#define NL 256
#define NH 512

typedef unsigned short ushort_t;
typedef short s16x8 __attribute__((ext_vector_type(8)));
typedef short s16x4 __attribute__((ext_vector_type(4)));
typedef float f32x4 __attribute__((ext_vector_type(4)));

__device__ __forceinline__ float wsum(float v){
  #pragma unroll
  for (int o = 32; o; o >>= 1) v += __shfl_xor(v, o);
  return v;
}
__device__ __forceinline__ float wmax(float v){
  #pragma unroll
  for (int o = 32; o; o >>= 1) v = fmaxf(v, __shfl_xor(v, o));
  return v;
}
__device__ __forceinline__ ushort_t f2bf(float f){
  union { float f; unsigned u; } v; v.f = f;
  unsigned r = v.u + 0x7fffu + ((v.u >> 16) & 1u);
  return (ushort_t)(r >> 16);
}

// ---------------------------------------------------------------------------
// kPrepAll (1141 blocks x 256):
//  bid <  512: hidden fp32 -> bf16 into A2 right half (lda 1024)
//  bid < 1024: WTG[n][k] bf16 gate-interleaved blockdiag GRU weight (2048x1024)
//  bid < 1056: WTA[c][k] = bf16 attn_W_bottom^T  (256x512)
//  bid < 1120: WTC[c][k] = bf16 comb_W_bottom^T  (512x512)
//  bid < 1132: p,q (attn top rank-2) / p2,q2 (comb top rank-2)
//  bid ==1132: stats = {mW, mb, Su2, Suv, Sv2}
//  bid > 1132: out0[b] = out_b[0]  (accumulator init for kGRU atomics)
// ---------------------------------------------------------------------------
__global__ __launch_bounds__(256)
void kPrepAll(const float* __restrict__ hidden,
              const float* __restrict__ eW, const float* __restrict__ eb,
              const float* __restrict__ attn_W, const float* __restrict__ comb_W,
              const float* __restrict__ Wih, const float* __restrict__ Whh,
              const float* __restrict__ out_b,
              ushort_t* __restrict__ A2, ushort_t* __restrict__ WTG,
              ushort_t* __restrict__ WTA, ushort_t* __restrict__ WTC,
              float* __restrict__ stats,
              float* __restrict__ p, float* __restrict__ q,
              float* __restrict__ p2, float* __restrict__ q2,
              float* __restrict__ out0)
{
  const int bid = blockIdx.x, tid = threadIdx.x;
  if (bid < 512) {                       // hidden -> bf16 A2 right half
    const int idx = (bid*256 + tid) * 8;
    const int b = idx >> 9, h = idx & 511;
    float4 v0 = *(const float4*)(hidden + idx);
    float4 v1 = *(const float4*)(hidden + idx + 4);
    s16x8 o;
    o[0]=f2bf(v0.x); o[1]=f2bf(v0.y); o[2]=f2bf(v0.z); o[3]=f2bf(v0.w);
    o[4]=f2bf(v1.x); o[5]=f2bf(v1.y); o[6]=f2bf(v1.z); o[7]=f2bf(v1.w);
    *(s16x8*)&A2[(size_t)b*1024 + 512 + h] = o;
    return;
  }
  if (bid < 1024) {                      // WTG bf16 gate-blockdiag
    const int b2 = bid - 512, bx = b2 & 31, by = b2 >> 5;
    const int n = bx*64 + (tid & 63);
    const int ksub = by*64 + (tid >> 6)*16;
    const int g = n >> 6, t = (n >> 4) & 3, c = (g << 4) | (n & 15);
    const int sc = (t == 0) ? c : (t == 1) ? (512 + c) : (1024 + c);
    ushort_t vals[16];
    #pragma unroll
    for (int kk = 0; kk < 16; ++kk) {
      int k = ksub + kk;
      float v;
      if (k < 512) v = (t == 3) ? 0.f : Wih[(size_t)k*1536 + sc];
      else         v = (t == 2) ? 0.f : Whh[(size_t)(k-512)*1536 + sc];
      vals[kk] = f2bf(v);
    }
    *(s16x8*)&WTG[(size_t)n*1024 + ksub]     = *(s16x8*)&vals[0];
    *(s16x8*)&WTG[(size_t)n*1024 + ksub + 8] = *(s16x8*)&vals[8];
    return;
  }
  if (bid < 1056) {                      // WTA bf16 transpose
    const int b2 = bid - 1024, bx = b2 & 3, by = b2 >> 2;
    const int c = bx*64 + (tid & 63);
    const int ksub = by*64 + (tid >> 6)*16;
    ushort_t vals[16];
    #pragma unroll
    for (int kk = 0; kk < 16; ++kk)
      vals[kk] = f2bf(attn_W[(size_t)(512 + ksub + kk)*NL + c]);
    *(s16x8*)&WTA[(size_t)c*512 + ksub]     = *(s16x8*)&vals[0];
    *(s16x8*)&WTA[(size_t)c*512 + ksub + 8] = *(s16x8*)&vals[8];
    return;
  }
  if (bid < 1120) {                      // WTC bf16 transpose
    const int b2 = bid - 1056, bx = b2 & 7, by = b2 >> 3;
    const int c = bx*64 + (tid & 63);
    const int ksub = by*64 + (tid >> 6)*16;
    ushort_t vals[16];
    #pragma unroll
    for (int kk = 0; kk < 16; ++kk)
      vals[kk] = f2bf(comb_W[(size_t)(512 + ksub + kk)*NH + c]);
    *(s16x8*)&WTC[(size_t)c*512 + ksub]     = *(s16x8*)&vals[0];
    *(s16x8*)&WTC[(size_t)c*512 + ksub + 8] = *(s16x8*)&vals[8];
    return;
  }
  if (bid > 1132) {                      // out0 init
    out0[(bid-1133)*256 + tid] = out_b[0];
    return;
  }
  // rank-2 projections + stats
  {
    __shared__ float rw[4], rb[4];
    __shared__ float pa[4][64], pb[4][64];
    const int lane = tid & 63, wv = tid >> 6;
    float swv = eW[tid] + eW[tid + 256];
    float sbv = eb[tid] + eb[tid + 256];
    swv = wsum(swv); sbv = wsum(sbv);
    if (lane == 0) { rw[wv] = swv; rb[wv] = sbv; }
    __syncthreads();
    const float mW = (rw[0]+rw[1]+rw[2]+rw[3]) * (1.f/NH);
    const float mb = (rb[0]+rb[1]+rb[2]+rb[3]) * (1.f/NH);

    if (bid == 1132) {
      float u0 = eW[tid]-mW, u1 = eW[tid+256]-mW;
      float v0 = eb[tid]-mb, v1 = eb[tid+256]-mb;
      float s2 = u0*u0 + u1*u1, s3 = u0*v0 + u1*v1, s4 = v0*v0 + v1*v1;
      s2 = wsum(s2); s3 = wsum(s3); s4 = wsum(s4);
      if (lane == 0) { pa[0][wv] = s2; pa[1][wv] = s3; pa[2][wv] = s4; }
      __syncthreads();
      if (tid == 0) {
        stats[0] = mW; stats[1] = mb;
        stats[2] = pa[0][0]+pa[0][1]+pa[0][2]+pa[0][3];
        stats[3] = pa[1][0]+pa[1][1]+pa[1][2]+pa[1][3];
        stats[4] = pa[2][0]+pa[2][1]+pa[2][2]+pa[2][3];
      }
      return;
    }
    const int bid2 = bid - 1120;
    const float* Wsrc; int ldw, c0; float *op, *oq;
    if (bid2 < 4) { Wsrc = attn_W; ldw = NL; c0 = bid2*64;     op = p  + c0; oq = q  + c0; }
    else          { Wsrc = comb_W; ldw = NH; c0 = (bid2-4)*64; op = p2 + c0; oq = q2 + c0; }
    const int c = c0 + lane;
    const int hc = tid >> 6;
    float ap = 0.f, aq = 0.f;
    #pragma unroll 4
    for (int h = hc*128; h < hc*128 + 128; ++h) {
      float w = Wsrc[(size_t)h*ldw + c];
      ap = fmaf(eW[h]-mW, w, ap);
      aq = fmaf(eb[h]-mb, w, aq);
    }
    pa[hc][lane] = ap; pb[hc][lane] = aq;
    __syncthreads();
    if (hc == 0) {
      op[lane] = pa[0][lane]+pa[1][lane]+pa[2][lane]+pa[3][lane];
      oq[lane] = pb[0][lane]+pb[1][lane]+pb[2][lane]+pb[3][lane];
    }
  }
}

// ---------------------------------------------------------------------------
// gemm_bf16<EPI>: 128x64 tile, 4 waves (4x1), wave = 32x64 (2x4 frags of
// 16x16x32 MFMA). C/D layout: col=lane&15, row=(lane>>4)*4+reg (m89-verified).
// EPI 1: logits = acc + attn_b + rank2 -> fp32 [2048][256] in ws
// EPI 2: xt = relu(acc + comb_b + rank2) -> bf16 at A2 left (ld 1024)
// EPI 3: GRU gates (j = gate) -> h_new fp32 + fused out0 atomic reduce
// ---------------------------------------------------------------------------
template<int EPI>
__global__ __launch_bounds__(256)
void gemm_bf16(const ushort_t* __restrict__ A, int lda,
               const ushort_t* __restrict__ Bt, int K,
               const float* __restrict__ xin, const float* __restrict__ stats,
               const float* __restrict__ pvec, const float* __restrict__ qvec,
               const float* __restrict__ bias,
               float* __restrict__ out_f, ushort_t* __restrict__ out_bf,
               const float* __restrict__ bih, const float* __restrict__ bhh,
               const float* __restrict__ hidden, const float* __restrict__ out_W,
               float* __restrict__ h_out, float* __restrict__ out0)
{
  __shared__ ushort_t As[128][72];
  __shared__ ushort_t Bs[64][72];
  const int tid = threadIdx.x, lane = tid & 63, wr = tid >> 6;
  const int m0 = blockIdx.x * 128, n0 = blockIdx.y * 64;

  f32x4 acc[2][4];
  #pragma unroll
  for (int i = 0; i < 2; ++i)
    #pragma unroll
    for (int j = 0; j < 4; ++j)
      acc[i][j] = (f32x4){0.f,0.f,0.f,0.f};

  const int srow = tid >> 3, scol = (tid & 7) * 8;
  for (int kt = 0; kt < K; kt += 64) {
    __syncthreads();
    #pragma unroll
    for (int it = 0; it < 4; ++it) {
      const int r = srow + it*32;
      *(s16x8*)&As[r][scol] = *(const s16x8*)&A[(size_t)(m0+r)*lda + kt + scol];
    }
    #pragma unroll
    for (int it = 0; it < 2; ++it) {
      const int r = srow + it*32;
      *(s16x8*)&Bs[r][scol] = *(const s16x8*)&Bt[(size_t)(n0+r)*K + kt + scol];
    }
    __syncthreads();
    #pragma unroll
    for (int ks = 0; ks < 2; ++ks) {
      const int ko = ks*32 + (lane >> 4)*8;
      s16x8 af[2], bfr[4];
      #pragma unroll
      for (int i = 0; i < 2; ++i) af[i]  = *(const s16x8*)&As[wr*32 + i*16 + (lane & 15)][ko];
      #pragma unroll
      for (int j = 0; j < 4; ++j) bfr[j] = *(const s16x8*)&Bs[j*16 + (lane & 15)][ko];
      #pragma unroll
      for (int i = 0; i < 2; ++i)
        #pragma unroll
        for (int j = 0; j < 4; ++j)
          acc[i][j] = __builtin_amdgcn_mfma_f32_16x16x32_bf16(af[i], bfr[j], acc[i][j], 0, 0, 0);
    }
  }

  if constexpr (EPI == 1 || EPI == 2) {
    const float S2 = stats[2], S3 = stats[3], S4 = stats[4];
    #pragma unroll
    for (int i = 0; i < 2; ++i) {
      #pragma unroll
      for (int reg = 0; reg < 4; ++reg) {
        const int row = m0 + wr*32 + i*16 + ((lane >> 4) << 2) + reg;
        const float xv = xin[row];
        const float rs = rsqrtf((xv*xv*S2 + 2.f*xv*S3 + S4)*(1.0f/NH) + 1e-5f);
        const float al = xv*rs, be = rs;
        #pragma unroll
        for (int j = 0; j < 4; ++j) {
          const int col = n0 + j*16 + (lane & 15);
          float v = acc[i][j][reg] + bias[col] + al*pvec[col] + be*qvec[col];
          if constexpr (EPI == 1) out_f[(size_t)row*NL + col] = v;
          else                    out_bf[(size_t)row*1024 + col] = f2bf(fmaxf(v, 0.f));
        }
      }
    }
  } else {  // EPI 3: GRU gates + fused output projection
    const int g = n0 >> 6;
    const int hcol = (g << 4) | (lane & 15);
    const float b_r = bih[hcol]        + bhh[hcol];
    const float b_z = bih[512 + hcol]  + bhh[512 + hcol];
    const float b_i = bih[1024 + hcol];
    const float b_h = bhh[1024 + hcol];
    const float ow  = out_W[hcol];
    #pragma unroll
    for (int i = 0; i < 2; ++i) {
      #pragma unroll
      for (int reg = 0; reg < 4; ++reg) {
        const int row = m0 + wr*32 + i*16 + ((lane >> 4) << 2) + reg;
        float rv = 1.f / (1.f + expf(-(acc[i][0][reg] + b_r)));
        float zv = 1.f / (1.f + expf(-(acc[i][1][reg] + b_z)));
        float nv = tanhf(acc[i][2][reg] + b_i + rv * (acc[i][3][reg] + b_h));
        float h0v = hidden[(size_t)row*NH + hcol];
        float hn = nv + zv * (h0v - nv);
        h_out[(size_t)row*NH + hcol] = hn;
        float partial = hn * ow;
        #pragma unroll
        for (int o = 1; o < 16; o <<= 1) partial += __shfl_xor(partial, o);
        if ((lane & 15) == 0) atomicAdd(&out0[row], partial);
      }
    }
  }
}

// ---------------------------------------------------------------------------
// kStream (2048 blocks x 256): per batch b:
//  softmax(logits[b]) -> attn_out (d_out) + wl (LDS)   [~1 us]
//  a[512] = sum_l wl[l]*enc[b,l,:]  -> bf16 ABF        [1.07 GB HBM stream]
// 256 thr = 4 waves; col = tid&127 (float4), row-half = tid>>7; partial
// sums combined via LDS. 2048 blocks x 4 waves = 32 waves/CU.
// ---------------------------------------------------------------------------
__global__ __launch_bounds__(256)
void kStream(const float* __restrict__ logits, const float* __restrict__ enc,
             float* __restrict__ attn_out, ushort_t* __restrict__ ABF)
{
  __shared__ float wl[NL];
  __shared__ __align__(16) float4 ps[128];
  __shared__ float sred[4];
  const int tid = threadIdx.x, lane = tid & 63, wv = tid >> 6;
  const int b = blockIdx.x;

  float lg = logits[(size_t)b*NL + tid];
  float m = wmax(lg);
  if (lane == 0) sred[wv] = m;
  __syncthreads();
  m = fmaxf(fmaxf(sred[0], sred[1]), fmaxf(sred[2], sred[3]));
  float e = expf(lg - m);
  float s = wsum(e);
  __syncthreads();
  if (lane == 0) sred[wv] = s;
  __syncthreads();
  const float inv = 1.f / (sred[0] + sred[1] + sred[2] + sred[3]);
  e *= inv;
  wl[tid] = e;
  attn_out[(size_t)b*NL + tid] = e;
  __syncthreads();

  const int col = tid & 127, half = tid >> 7;
  const float4* ep = (const float4*)(enc + (size_t)b*NL*NH);
  float4 acc = {0.f,0.f,0.f,0.f};
  #pragma unroll 4
  for (int l = half*128; l < half*128 + 128; ++l) {
    float w = wl[l];
    float4 ev = ep[l*(NH/4) + col];
    acc.x = fmaf(w,ev.x,acc.x); acc.y = fmaf(w,ev.y,acc.y);
    acc.z = fmaf(w,ev.z,acc.z); acc.w = fmaf(w,ev.w,acc.w);
  }
  if (half == 0) ps[col] = acc;
  __syncthreads();
  if (half == 1) {
    float4 o = ps[col];
    o.x += acc.x; o.y += acc.y; o.z += acc.z; o.w += acc.w;
    s16x4 ov; ov[0]=f2bf(o.x); ov[1]=f2bf(o.y); ov[2]=f2bf(o.z); ov[3]=f2bf(o.w);
    *(s16x4*)&ABF[(size_t)b*NH + col*4] = ov;
  }
}

// ---------------------------------------------------------------------------
extern "C" void kernel_launch(void* const* d_in, const int* in_sizes, int n_in,
                              void* d_out, int out_size, void* d_ws, size_t ws_size,
                              hipStream_t stream)
{
  const float* x      = (const float*)d_in[0];
  const float* hidden = (const float*)d_in[1];
  const float* enc    = (const float*)d_in[2];
  const float* emb_W  = (const float*)d_in[3];
  const float* emb_b  = (const float*)d_in[4];
  const float* attn_W = (const float*)d_in[5];
  const float* attn_b = (const float*)d_in[6];
  const float* comb_W = (const float*)d_in[7];
  const float* comb_b = (const float*)d_in[8];
  const float* Wih    = (const float*)d_in[9];
  const float* Whh    = (const float*)d_in[10];
  const float* bih    = (const float*)d_in[11];
  const float* bhh    = (const float*)d_in[12];
  const float* out_W  = (const float*)d_in[13];
  const float* out_b  = (const float*)d_in[14];

  float* out      = (float*)d_out;
  float* out0     = out;                          // 2048
  float* out_h    = out + NB;                     // B*H
  float* out_attn = out + NB + (size_t)NB*NH;     // B*L

  float* wsf    = (float*)d_ws;
  float* stats  = wsf;              // 16
  float* p      = wsf + 16;         // 256
  float* q      = wsf + 272;        // 256
  float* p2     = wsf + 528;        // 512
  float* q2     = wsf + 1040;       // 512
  float* logits = wsf + 2048;       // [2048][256] fp32
  ushort_t* usb = (ushort_t*)(wsf + 526400);
  ushort_t* A2  = usb;              // [2048][1024] bf16: [xt | h0]
  ushort_t* ABF = usb + 2097152;    // [2048][512]  bf16 attn_applied
  ushort_t* WTA = usb + 3145728;    // [256][512]
  ushort_t* WTC = usb + 3276800;    // [512][512]
  ushort_t* WTG = usb + 3538944;    // [2048][1024]

  kPrepAll<<<1141, 256, 0, stream>>>(hidden, emb_W, emb_b, attn_W, comb_W,
                                     Wih, Whh, out_b, A2, WTG, WTA, WTC,
                                     stats, p, q, p2, q2, out0);
  // logits = h0 @ attn_W_bot + rank2 + bias  (M=2048, N=256, K=512)
  gemm_bf16<1><<<dim3(16, 4), 256, 0, stream>>>(A2 + 512, 1024, WTA, 512,
      x, stats, p, q, attn_b, logits, nullptr,
      nullptr, nullptr, nullptr, nullptr, nullptr, nullptr);
  kStream<<<NB, 256, 0, stream>>>(logits, enc, out_attn, ABF);
  // xt = relu(a @ comb_W_bot + rank2 + bias) -> A2 left (M=2048,N=512,K=512)
  gemm_bf16<2><<<dim3(16, 8), 256, 0, stream>>>(ABF, 512, WTC, 512,
      x, stats, p2, q2, comb_b, nullptr, A2,
      nullptr, nullptr, nullptr, nullptr, nullptr, nullptr);
  // GRU: [xt|h0] @ WTG^T + gates + fused out0 (M=2048,N=2048,K=1024)
  gemm_bf16<3><<<dim3(16, 32), 256, 0, stream>>>(A2, 1024, WTG, 1024,
      nullptr, nullptr, nullptr, nullptr, nullptr, nullptr, nullptr,
      bih, bhh, hidden, out_W, out_h, out0);
}